// Round 5
// baseline (50.594 us; speedup 1.0000x reference)
//
#include <hip/hip_runtime.h>

#define NUM_F 256
#define DIM 128
#define LN_EPS 1e-5f

typedef float f32x4 __attribute__((ext_vector_type(4)));

// Single fused kernel, single occupancy round (grid=2048, 8 blocks/CU).
// Wave layout: lanes 0-31 -> row 2p, lanes 32-63 -> row 2p+1; each lane owns a
// float4 (16B) of the 128-dim row; one wave64 store = 1 KiB contiguous (2 rows).
// rstep = 2*nwaves is a multiple of NUM_F, so each wave-half's feature f is
// CONSTANT across its grid-stride iterations -> all per-feature data hoisted.
//
// Closed-form LayerNorm stats (per feature f, computed once per wave via
// shfl_xor offsets 1..16, which stay within each 32-lane half):
//   mean(t) = x*mw + mc ;  E[t^2] = x^2*kx2 + x*kx1 + k0 ;  var = E[t^2]-mean^2
//
// Main loop: NIT=32 iterations, x prefetched in register batches of 8 (next
// batch's 8 independent loads issued before current batch's compute+stores),
// so stores never wait on loads.
__global__ __launch_bounds__(256) void ft_fused_kernel(
    const float* __restrict__ x,      // (B, F)
    const float* __restrict__ W,      // (F, D)
    const float* __restrict__ bvec,   // (F, D)
    const float* __restrict__ E,      // (F, D)
    const float* __restrict__ gamma,  // (D,)
    const float* __restrict__ beta,   // (D,)
    float* __restrict__ out,          // (B, F, D)
    int nrows)
{
    const int lane   = threadIdx.x & 63;
    const int lane32 = lane & 31;
    const int half   = lane >> 5;
    const int gwave  = blockIdx.x * 4 + (threadIdx.x >> 6);
    const int nwaves = gridDim.x * 4;

    const int row0  = 2 * gwave + half;
    const int rstep = 2 * nwaves;              // multiple of NUM_F by construction
    const int f     = row0 & (NUM_F - 1);      // constant per wave-half
    const int dbase = lane32 * 4;

    const f32x4 w  = *reinterpret_cast<const f32x4*>(W    + f * DIM + dbase);
    const f32x4 bv = *reinterpret_cast<const f32x4*>(bvec + f * DIM + dbase);
    const f32x4 ev = *reinterpret_cast<const f32x4*>(E    + f * DIM + dbase);
    const f32x4 g  = *reinterpret_cast<const f32x4*>(gamma + dbase);
    const f32x4 bt = *reinterpret_cast<const f32x4*>(beta  + dbase);
    const f32x4 cv = bv + ev;

    // ---- one-time per-feature reduction (within each 32-lane half) ----
    float sw  = (w.x + w.y) + (w.z + w.w);
    float sc  = (cv.x + cv.y) + (cv.z + cv.w);
    float sww = (w.x*w.x + w.y*w.y) + (w.z*w.z + w.w*w.w);
    float swc = (w.x*cv.x + w.y*cv.y) + (w.z*cv.z + w.w*cv.w);
    float scc = (cv.x*cv.x + cv.y*cv.y) + (cv.z*cv.z + cv.w*cv.w);
    #pragma unroll
    for (int off = 16; off >= 1; off >>= 1) {
        sw  += __shfl_xor(sw,  off, 64);
        sc  += __shfl_xor(sc,  off, 64);
        sww += __shfl_xor(sww, off, 64);
        swc += __shfl_xor(swc, off, 64);
        scc += __shfl_xor(scc, off, 64);
    }
    const float inv = 1.0f / (float)DIM;
    const float mw  = sw  * inv;
    const float mc  = sc  * inv;
    const float kx2 = sww * inv;
    const float kx1 = 2.0f * swc * inv;
    const float k0  = scc * inv;

    float* const obase = out + dbase;

#define FT_COMPUTE_STORE(XV, ROW)                                             \
    {                                                                         \
        const float xv_  = (XV);                                              \
        const float mean = fmaf(xv_, mw, mc);                                 \
        const float exx  = fmaf(xv_ * xv_, kx2, fmaf(xv_, kx1, k0));          \
        const float var  = fmaf(-mean, mean, exx);                            \
        const float A    = rsqrtf(var + LN_EPS);                              \
        const float Bc   = -mean * A;                                         \
        f32x4 o;                                                              \
        o.x = fmaf(fmaf(fmaf(xv_, w.x, cv.x), A, Bc), g.x, bt.x);             \
        o.y = fmaf(fmaf(fmaf(xv_, w.y, cv.y), A, Bc), g.y, bt.y);             \
        o.z = fmaf(fmaf(fmaf(xv_, w.z, cv.z), A, Bc), g.z, bt.z);             \
        o.w = fmaf(fmaf(fmaf(xv_, w.w, cv.w), A, Bc), g.w, bt.w);             \
        *reinterpret_cast<f32x4*>(obase + (size_t)(ROW) * DIM) = o;           \
    }

    if (rstep * 32 == nrows) {
        // ---- specialized: 32 iterations, x prefetched 8 ahead ----
        float xv[8];
        #pragma unroll
        for (int k = 0; k < 8; ++k) xv[k] = x[row0 + k * rstep];

        #pragma unroll
        for (int b = 0; b < 4; ++b) {
            float xn[8];
            if (b < 3) {
                #pragma unroll
                for (int k = 0; k < 8; ++k)
                    xn[k] = x[row0 + (b * 8 + 8 + k) * rstep];
            }
            #pragma unroll
            for (int k = 0; k < 8; ++k)
                FT_COMPUTE_STORE(xv[k], row0 + (b * 8 + k) * rstep);
            if (b < 3) {
                #pragma unroll
                for (int k = 0; k < 8; ++k) xv[k] = xn[k];
            }
        }
    } else {
        for (int row = row0; row < nrows; row += rstep)
            FT_COMPUTE_STORE(x[row], row);
    }
#undef FT_COMPUTE_STORE
}

extern "C" void kernel_launch(void* const* d_in, const int* in_sizes, int n_in,
                              void* d_out, int out_size, void* d_ws, size_t ws_size,
                              hipStream_t stream) {
    const float* x     = (const float*)d_in[0];   // (B, F)
    const float* W     = (const float*)d_in[1];   // (F, D)
    const float* bvec  = (const float*)d_in[2];   // (F, D)
    const float* E     = (const float*)d_in[3];   // (F, D)
    const float* gamma = (const float*)d_in[4];   // (D,)
    const float* beta  = (const float*)d_in[5];   // (D,)
    float* out = (float*)d_out;

    const int B = in_sizes[0] / NUM_F;
    const int nrows = B * NUM_F;

    // grid=2048: 8 blocks/CU, ONE occupancy round; rstep=16384 (multiple of
    // NUM_F -> f constant per wave-half); NIT = nrows/rstep = 32 for B=2048.
    const int block = 256;                        // 4 waves/block
    const int grid  = 2048;
    ft_fused_kernel<<<grid, block, 0, stream>>>(
        x, W, bvec, E, gamma, beta, out, nrows);
}

// Round 6
// 47.028 us; speedup vs baseline: 1.0758x; 1.0758x over previous
//
#include <hip/hip_runtime.h>

#define NUM_F 256
#define DIM 128
#define LN_EPS 1e-5f

typedef float f32x4 __attribute__((ext_vector_type(4)));

// Single fused kernel. grid=8192, NIT=8.
// Wave layout: lanes 0-31 -> row 2p, lanes 32-63 -> row 2p+1; each lane owns a
// float4 (16B) of the 128-dim row; one wave64 store = 1 KiB contiguous (2 rows).
// rstep = 2*nwaves (65536) is a multiple of NUM_F, so each wave-half's feature
// f is CONSTANT across its grid-stride iterations.
//
// VMEM-queue discipline (R5 lesson): ALL x loads are issued at the very top of
// the kernel, BEFORE any store, so vmcnt waits on loads never force stores to
// retire. Their latency hides under the constant-load + shuffle prologue.
//
// Closed-form LayerNorm stats (per feature f, once per wave, shfl_xor offsets
// 1..16 stay within each 32-lane half):
//   mean(t) = x*mw + mc ;  E[t^2] = x^2*kx2 + x*kx1 + k0 ;  var = E[t^2]-mean^2
__global__ __launch_bounds__(256) void ft_fused_kernel(
    const float* __restrict__ x,      // (B, F)
    const float* __restrict__ W,      // (F, D)
    const float* __restrict__ bvec,   // (F, D)
    const float* __restrict__ E,      // (F, D)
    const float* __restrict__ gamma,  // (D,)
    const float* __restrict__ beta,   // (D,)
    float* __restrict__ out,          // (B, F, D)
    int nrows)
{
    const int lane   = threadIdx.x & 63;
    const int lane32 = lane & 31;
    const int half   = lane >> 5;
    const int gwave  = blockIdx.x * 4 + (threadIdx.x >> 6);
    const int nwaves = gridDim.x * 4;

    const int row0  = 2 * gwave + half;
    const int rstep = 2 * nwaves;              // multiple of NUM_F by construction
    const int f     = row0 & (NUM_F - 1);      // constant per wave-half
    const int dbase = lane32 * 4;

    const bool fast = (rstep * 8 == nrows);

    // ---- issue ALL x loads first (oldest in the VMEM queue) ----
    float xv[8];
    if (fast) {
        #pragma unroll
        for (int k = 0; k < 8; ++k) xv[k] = x[row0 + k * rstep];
    }

    const f32x4 w  = *reinterpret_cast<const f32x4*>(W    + f * DIM + dbase);
    const f32x4 bv = *reinterpret_cast<const f32x4*>(bvec + f * DIM + dbase);
    const f32x4 ev = *reinterpret_cast<const f32x4*>(E    + f * DIM + dbase);
    const f32x4 g  = *reinterpret_cast<const f32x4*>(gamma + dbase);
    const f32x4 bt = *reinterpret_cast<const f32x4*>(beta  + dbase);
    const f32x4 cv = bv + ev;

    // ---- one-time per-feature reduction (within each 32-lane half) ----
    float sw  = (w.x + w.y) + (w.z + w.w);
    float sc  = (cv.x + cv.y) + (cv.z + cv.w);
    float sww = (w.x*w.x + w.y*w.y) + (w.z*w.z + w.w*w.w);
    float swc = (w.x*cv.x + w.y*cv.y) + (w.z*cv.z + w.w*cv.w);
    float scc = (cv.x*cv.x + cv.y*cv.y) + (cv.z*cv.z + cv.w*cv.w);
    #pragma unroll
    for (int off = 16; off >= 1; off >>= 1) {
        sw  += __shfl_xor(sw,  off, 64);
        sc  += __shfl_xor(sc,  off, 64);
        sww += __shfl_xor(sww, off, 64);
        swc += __shfl_xor(swc, off, 64);
        scc += __shfl_xor(scc, off, 64);
    }
    const float inv = 1.0f / (float)DIM;
    const float mw  = sw  * inv;
    const float mc  = sc  * inv;
    const float kx2 = sww * inv;
    const float kx1 = 2.0f * swc * inv;
    const float k0  = scc * inv;

    float* const obase = out + dbase;

#define FT_COMPUTE_STORE(XV, ROW)                                             \
    {                                                                         \
        const float xv_  = (XV);                                              \
        const float mean = fmaf(xv_, mw, mc);                                 \
        const float exx  = fmaf(xv_ * xv_, kx2, fmaf(xv_, kx1, k0));          \
        const float var  = fmaf(-mean, mean, exx);                            \
        const float A    = rsqrtf(var + LN_EPS);                              \
        const float Bc   = -mean * A;                                         \
        f32x4 o;                                                              \
        o.x = fmaf(fmaf(fmaf(xv_, w.x, cv.x), A, Bc), g.x, bt.x);             \
        o.y = fmaf(fmaf(fmaf(xv_, w.y, cv.y), A, Bc), g.y, bt.y);             \
        o.z = fmaf(fmaf(fmaf(xv_, w.z, cv.z), A, Bc), g.z, bt.z);             \
        o.w = fmaf(fmaf(fmaf(xv_, w.w, cv.w), A, Bc), g.w, bt.w);             \
        *reinterpret_cast<f32x4*>(obase + (size_t)(ROW) * DIM) = o;           \
    }

    if (fast) {
        #pragma unroll
        for (int k = 0; k < 8; ++k)
            FT_COMPUTE_STORE(xv[k], row0 + k * rstep);
    } else {
        for (int row = row0; row < nrows; row += rstep)
            FT_COMPUTE_STORE(x[row], row);
    }
#undef FT_COMPUTE_STORE
}

extern "C" void kernel_launch(void* const* d_in, const int* in_sizes, int n_in,
                              void* d_out, int out_size, void* d_ws, size_t ws_size,
                              hipStream_t stream) {
    const float* x     = (const float*)d_in[0];   // (B, F)
    const float* W     = (const float*)d_in[1];   // (F, D)
    const float* bvec  = (const float*)d_in[2];   // (F, D)
    const float* E     = (const float*)d_in[3];   // (F, D)
    const float* gamma = (const float*)d_in[4];   // (D,)
    const float* beta  = (const float*)d_in[5];   // (D,)
    float* out = (float*)d_out;

    const int B = in_sizes[0] / NUM_F;
    const int nrows = B * NUM_F;

    // grid=8192: rstep = 8*grid = 65536 rows (multiple of NUM_F -> f constant
    // per wave-half); NIT = nrows/rstep = 8 for B=2048.
    const int block = 256;                        // 4 waves/block
    int grid = 8192;
    if (nrows % (8 * grid) != 0) grid = 2048;     // fallback: generic loop path
    ft_fused_kernel<<<grid, block, 0, stream>>>(
        x, W, bvec, E, gamma, beta, out, nrows);
}